// Round 1
// 97.463 us; speedup vs baseline: 1.0401x; 1.0401x over previous
//
#include <hip/hip_runtime.h>

// Problem constants (B, N_NODE, FN, FE) = (8, 128, 64, 64)
// Single fused kernel: each block (b, j-tile16, i-chunk16) computes
//   out[b,j,l] = sum_i sigmoid(att)*relu(conv),
//   att/conv = A[b,i,j]*(Pi[i,l]+Pj[j,l]+(E@We)[b,i,j,l]) + bias
//
// R1 vs baseline: the prologue was 4x wave-redundant (all fragment builds and
// the Pi/Pj MFMAs are independent of the wave id). Now: each wave builds 12 of
// the 48 W fragments (global scatter /4), shares via LDS b128 ops; Pi/Pj MFMAs
// computed once per (br,t) pair (8 MFMAs/wave vs 32) and shared via LDS
// (replaces the 32 shfls too). Main loop / epilogue / numerics unchanged.

typedef _Float16 half8 __attribute__((ext_vector_type(8)));
typedef float floatx4 __attribute__((ext_vector_type(4)));

__device__ __forceinline__ half8 cvt2(const float4 a, const float4 b) {
  half8 v;
  v[0] = (_Float16)a.x; v[1] = (_Float16)a.y; v[2] = (_Float16)a.z; v[3] = (_Float16)a.w;
  v[4] = (_Float16)b.x; v[5] = (_Float16)b.y; v[6] = (_Float16)b.z; v[7] = (_Float16)b.w;
  return v;
}

__global__ __launch_bounds__(256, 2)
void amp_fused(const float* __restrict__ H, const float* __restrict__ A,
               const float* __restrict__ E,
               const float* __restrict__ Wa, const float* __restrict__ Wn,
               const float* __restrict__ ba, const float* __restrict__ bn,
               float* __restrict__ out) {
  const int bx = blockIdx.x;  // 0..511
  const int b = bx >> 6;      // 0..7
  const int rem = bx & 63;
  const int jt = rem >> 3;    // 0..7  j tile of 16
  const int ch = rem & 7;     // 0..7  i chunk of 16
  const int w = threadIdx.x >> 6;   // wave in block
  const int lane = threadIdx.x & 63;
  const int quad = lane >> 4;
  const int l15 = lane & 15;
  const int i0b = ch * 16;          // block's i chunk base
  const int i0 = i0b + w * 4;       // this wave's 4 i's
  const int j0 = jt * 16;
  const float* Wptr[2] = {Wa, Wn};

  // 48 KB LDS: fragment area [48 frags][64 lanes][16 B].
  // pif/pjf (16 KB) alias frags F0..15 (bi, dead after stage 2 reads);
  // epilogue red (16 KB) aliases the same region. Barriers guard each alias.
  __shared__ __align__(16) char smem[48 * 1024];
  _Float16* fraglds = reinterpret_cast<_Float16*>(smem);
  float* pflds = reinterpret_cast<float*>(smem);              // 8 KB
  float* pjlds = reinterpret_cast<float*>(smem + 8 * 1024);   // 8 KB
  float (*red)[16][64] = reinterpret_cast<float (*)[16][64]>(smem);

  // ---- H fragments (A-operand layout: row=l15, k=quad*8+x+hh*32) ----
  half8 hi[2], hj[2];
  {
    const float* hib = H + (b * 128 + i0b + l15) * 64 + quad * 8;
    const float* hjb = H + (b * 128 + j0 + l15) * 64 + quad * 8;
#pragma unroll
    for (int hh = 0; hh < 2; ++hh) {
      hi[hh] = cvt2(*reinterpret_cast<const float4*>(hib + hh * 32),
                    *reinterpret_cast<const float4*>(hib + hh * 32 + 4));
      hj[hh] = cvt2(*reinterpret_cast<const float4*>(hjb + hh * 32),
                    *reinterpret_cast<const float4*>(hjb + hh * 32 + 4));
    }
  }

  // ---- Stage 1: cooperative W-fragment build, 12 of 48 per wave ----
  // F = kind*16 + br*8 + t*2 + hh; kind 0=Wi(rows 0..63) 1=Wj(64..127) 2=We(128..191)
#pragma unroll
  for (int k = 0; k < 12; ++k) {
    const int F = w * 12 + k;
    const int kind = F >> 4;
    const int f = F & 15;
    const int br = f >> 3;
    const int t = (f >> 1) & 3;
    const int hh = f & 1;
    const float* src = Wptr[br] + (kind * 64 + hh * 32 + quad * 8) * 64 + t * 16 + l15;
    half8 v;
#pragma unroll
    for (int x = 0; x < 8; ++x) v[x] = (_Float16)src[x * 64];
    *reinterpret_cast<half8*>(fraglds + F * 512 + lane * 8) = v;
  }
  __syncthreads();

  // ---- Stage 2: Pi/Pj projection MFMAs, 2 (br,t) pairs per wave ----
  floatx4 pif[2], pjf[2];
#pragma unroll
  for (int pp = 0; pp < 2; ++pp) {
    const int p = w * 2 + pp;   // 0..7
    const int br = p >> 2;
    const int t = p & 3;
    floatx4 z = {0.f, 0.f, 0.f, 0.f};
    pif[pp] = z; pjf[pp] = z;
#pragma unroll
    for (int hh = 0; hh < 2; ++hh) {
      half8 bi = *reinterpret_cast<half8*>(fraglds + (br * 8 + t * 2 + hh) * 512 + lane * 8);
      half8 bj = *reinterpret_cast<half8*>(fraglds + (16 + br * 8 + t * 2 + hh) * 512 + lane * 8);
      pif[pp] = __builtin_amdgcn_mfma_f32_16x16x32_f16(hi[hh], bi, pif[pp], 0, 0, 0);
      pjf[pp] = __builtin_amdgcn_mfma_f32_16x16x32_f16(hj[hh], bj, pjf[pp], 0, 0, 0);
    }
  }
  __syncthreads();  // all bi/bj frag reads done before writing the aliased pf/pj area
#pragma unroll
  for (int pp = 0; pp < 2; ++pp) {
    const int p = w * 2 + pp;
    *reinterpret_cast<floatx4*>(pflds + (p * 64 + lane) * 4) = pif[pp];
    *reinterpret_cast<floatx4*>(pjlds + (p * 64 + lane) * 4) = pjf[pp];
  }
  __syncthreads();

  // ---- Stage 3: per-wave pickup of Pi/Pj results and We fragments ----
  // pif C-layout at source lane w*16+l15, reg ii  ==  Pi[i0+ii][t*16+l15]
  // pjf C-layout at own lane, reg r               ==  Pj[j0+quad*4+r][t*16+l15]
  float pia_all[2][4][4];
  float pj[2][4][4];
  half8 wf[2][4][2];
#pragma unroll
  for (int br = 0; br < 2; ++br)
#pragma unroll
    for (int t = 0; t < 4; ++t) {
      const int p = br * 4 + t;
      const floatx4 pjv = *reinterpret_cast<const floatx4*>(pjlds + (p * 64 + lane) * 4);
      const floatx4 piv = *reinterpret_cast<const floatx4*>(pflds + (p * 64 + w * 16 + l15) * 4);
#pragma unroll
      for (int r = 0; r < 4; ++r) { pj[br][t][r] = pjv[r]; pia_all[br][t][r] = piv[r]; }
#pragma unroll
      for (int hh = 0; hh < 2; ++hh)
        wf[br][t][hh] = *reinterpret_cast<half8*>(
            fraglds + (32 + br * 8 + t * 2 + hh) * 512 + lane * 8);
    }

  float biasv[2][4];
#pragma unroll
  for (int t = 0; t < 4; ++t) {
    biasv[0][t] = ba[t * 16 + l15];
    biasv[1][t] = bn[t * 16 + l15];
  }

  float acc[4][4];
#pragma unroll
  for (int t = 0; t < 4; ++t)
#pragma unroll
    for (int r = 0; r < 4; ++r) acc[t][r] = 0.f;

  // ---- Main loop over this wave's 4 i's (unchanged) ----
#pragma unroll
  for (int ii = 0; ii < 4; ++ii) {
    const int i = i0 + ii;
    const float* erow = E + ((size_t)((b * 128 + i) * 128 + j0 + l15)) * 64 + quad * 8;
    half8 a0 = cvt2(*reinterpret_cast<const float4*>(erow),
                    *reinterpret_cast<const float4*>(erow + 4));
    half8 a1 = cvt2(*reinterpret_cast<const float4*>(erow + 32),
                    *reinterpret_cast<const float4*>(erow + 36));

    const float4 av4 = *reinterpret_cast<const float4*>(
        A + (b * 128 + i) * 128 + j0 + quad * 4);
    const float av[4] = {av4.x, av4.y, av4.z, av4.w};

#pragma unroll
    for (int t = 0; t < 4; ++t) {
      floatx4 z = {0.f, 0.f, 0.f, 0.f};
      floatx4 pa = __builtin_amdgcn_mfma_f32_16x16x32_f16(a0, wf[0][t][0], z, 0, 0, 0);
      pa = __builtin_amdgcn_mfma_f32_16x16x32_f16(a1, wf[0][t][1], pa, 0, 0, 0);
      floatx4 pn = __builtin_amdgcn_mfma_f32_16x16x32_f16(a0, wf[1][t][0], z, 0, 0, 0);
      pn = __builtin_amdgcn_mfma_f32_16x16x32_f16(a1, wf[1][t][1], pn, 0, 0, 0);
#pragma unroll
      for (int r = 0; r < 4; ++r) {
        float att = av[r] * (pa[r] + pia_all[0][t][ii] + pj[0][t][r]) + biasv[0][t];
        float cnv = av[r] * (pn[r] + pia_all[1][t][ii] + pj[1][t][r]) + biasv[1][t];
        float ex = __expf(-att);
        float sig = __builtin_amdgcn_rcpf(1.0f + ex);
        acc[t][r] += sig * fmaxf(cnv, 0.f);
      }
    }
  }

  // ---- Epilogue: intra-block reduce (4 waves), then 8-contender atomics ----
  __syncthreads();  // everyone past stage-3 reads before red aliases pf/pj
#pragma unroll
  for (int t = 0; t < 4; ++t)
#pragma unroll
    for (int r = 0; r < 4; ++r)
      red[w][quad * 4 + r][t * 16 + l15] = acc[t][r];
  __syncthreads();

  const int tid = threadIdx.x;
#pragma unroll
  for (int k = 0; k < 4; ++k) {
    int idx = k * 256 + tid;       // 0..1023 over the 16x64 out tile
    int jl = idx >> 6;
    int l = idx & 63;
    float s = red[0][jl][l] + red[1][jl][l] + red[2][jl][l] + red[3][jl][l];
    atomicAdd(out + (b * 128 + j0 + jl) * 64 + l, s);
  }
}

extern "C" void kernel_launch(void* const* d_in, const int* in_sizes, int n_in,
                              void* d_out, int out_size, void* d_ws, size_t ws_size,
                              hipStream_t stream) {
  const float* H = (const float*)d_in[0];
  const float* A = (const float*)d_in[1];
  const float* E = (const float*)d_in[2];
  const float* Wa = (const float*)d_in[3];
  const float* Wn = (const float*)d_in[4];
  const float* ba = (const float*)d_in[5];
  const float* bn = (const float*)d_in[6];
  float* out = (float*)d_out;

  hipMemsetAsync(d_out, 0, (size_t)out_size * sizeof(float), stream);
  amp_fused<<<512, 256, 0, stream>>>(H, A, E, Wa, Wn, ba, bn, out);
}

// Round 3
// 95.092 us; speedup vs baseline: 1.0660x; 1.0249x over previous
//
#include <hip/hip_runtime.h>

// Problem constants (B, N_NODE, FN, FE) = (8, 128, 64, 64)
// Single fused kernel: each block (b, j-tile16, i-chunk16) computes
//   out[b,j,l] = sum_i sigmoid(att)*relu(conv),
//   att/conv = A[b,i,j]*(Pi[i,l]+Pj[j,l]+(E@We)[b,i,j,l]) + bias
//
// R3 = R2 with the cvt_pkrtz return-type fix (__fp16 vector, not _Float16).
// R2 vs R1:
//  - E/A prefetch for ii=0,1 issued at kernel top: HBM stream starts before
//    the W-fragment prologue instead of idling behind it.
//  - pif/pjf moved to a dedicated 16 KB LDS region (64 KB total, still
//    2 blocks/CU): stage-2 alias barrier removed; pre-epilogue barrier
//    removed (red only overlaps bi frags, dead after stage 2). 5 -> 3 barriers.
//  - All f32->f16 conversions via v_cvt_pk_rtz_f16_f32 (4 instr/half8 vs ~12).

typedef _Float16 half8 __attribute__((ext_vector_type(8)));
typedef __fp16 fp16x2 __attribute__((ext_vector_type(2)));
typedef float floatx4 __attribute__((ext_vector_type(4)));

__device__ __forceinline__ half8 cvt2(const float4 a, const float4 b) {
  union { fp16x2 h2[4]; half8 h8; } u;
  u.h2[0] = __builtin_amdgcn_cvt_pkrtz(a.x, a.y);
  u.h2[1] = __builtin_amdgcn_cvt_pkrtz(a.z, a.w);
  u.h2[2] = __builtin_amdgcn_cvt_pkrtz(b.x, b.y);
  u.h2[3] = __builtin_amdgcn_cvt_pkrtz(b.z, b.w);
  return u.h8;
}

__global__ __launch_bounds__(256, 2)
void amp_fused(const float* __restrict__ H, const float* __restrict__ A,
               const float* __restrict__ E,
               const float* __restrict__ Wa, const float* __restrict__ Wn,
               const float* __restrict__ ba, const float* __restrict__ bn,
               float* __restrict__ out) {
  const int bx = blockIdx.x;  // 0..511
  const int b = bx >> 6;      // 0..7
  const int rem = bx & 63;
  const int jt = rem >> 3;    // 0..7  j tile of 16
  const int ch = rem & 7;     // 0..7  i chunk of 16
  const int w = threadIdx.x >> 6;   // wave in block
  const int lane = threadIdx.x & 63;
  const int quad = lane >> 4;
  const int l15 = lane & 15;
  const int i0b = ch * 16;          // block's i chunk base
  const int i0 = i0b + w * 4;       // this wave's 4 i's
  const int j0 = jt * 16;
  const float* Wptr[2] = {Wa, Wn};

  // 64 KB LDS: [0,48K) fragment area [48 frags][64 lanes][16 B];
  // [48K,56K) pif results, [56K,64K) pjf results (no aliasing -> fewer
  // barriers). Epilogue red (16 KB) aliases frags F0..15 (dead after stage 2).
  __shared__ __align__(16) char smem[64 * 1024];
  _Float16* fraglds = reinterpret_cast<_Float16*>(smem);
  float* pflds = reinterpret_cast<float*>(smem + 48 * 1024);  // 8 KB
  float* pjlds = reinterpret_cast<float*>(smem + 56 * 1024);  // 8 KB
  float (*red)[16][64] = reinterpret_cast<float (*)[16][64]>(smem);

  // ---- E/A prefetch for ii=0,1: get the HBM stream going before the
  //      (L2-bound, latency-serial) W prologue ----
  float4 e_pf[2][4];
  float4 a_pf[2];
#pragma unroll
  for (int ii = 0; ii < 2; ++ii) {
    const float* erow = E + ((size_t)((b * 128 + i0 + ii) * 128 + j0 + l15)) * 64 + quad * 8;
    e_pf[ii][0] = *reinterpret_cast<const float4*>(erow);
    e_pf[ii][1] = *reinterpret_cast<const float4*>(erow + 4);
    e_pf[ii][2] = *reinterpret_cast<const float4*>(erow + 32);
    e_pf[ii][3] = *reinterpret_cast<const float4*>(erow + 36);
    a_pf[ii] = *reinterpret_cast<const float4*>(A + (b * 128 + i0 + ii) * 128 + j0 + quad * 4);
  }

  float biasv[2][4];
#pragma unroll
  for (int t = 0; t < 4; ++t) {
    biasv[0][t] = ba[t * 16 + l15];
    biasv[1][t] = bn[t * 16 + l15];
  }

  // ---- H fragments (A-operand layout: row=l15, k=quad*8+x+hh*32) ----
  half8 hi[2], hj[2];
  {
    const float* hib = H + (b * 128 + i0b + l15) * 64 + quad * 8;
    const float* hjb = H + (b * 128 + j0 + l15) * 64 + quad * 8;
#pragma unroll
    for (int hh = 0; hh < 2; ++hh) {
      hi[hh] = cvt2(*reinterpret_cast<const float4*>(hib + hh * 32),
                    *reinterpret_cast<const float4*>(hib + hh * 32 + 4));
      hj[hh] = cvt2(*reinterpret_cast<const float4*>(hjb + hh * 32),
                    *reinterpret_cast<const float4*>(hjb + hh * 32 + 4));
    }
  }

  // ---- Stage 1: cooperative W-fragment build, 12 of 48 per wave ----
  // F = kind*16 + br*8 + t*2 + hh; kind 0=Wi(rows 0..63) 1=Wj(64..127) 2=We(128..191)
#pragma unroll
  for (int k = 0; k < 12; ++k) {
    const int F = w * 12 + k;
    const int kind = F >> 4;
    const int f = F & 15;
    const int br = f >> 3;
    const int t = (f >> 1) & 3;
    const int hh = f & 1;
    const float* src = Wptr[br] + (kind * 64 + hh * 32 + quad * 8) * 64 + t * 16 + l15;
    union { fp16x2 h2[4]; half8 h8; } u;
#pragma unroll
    for (int x = 0; x < 4; ++x)
      u.h2[x] = __builtin_amdgcn_cvt_pkrtz(src[(2 * x) * 64], src[(2 * x + 1) * 64]);
    *reinterpret_cast<half8*>(fraglds + F * 512 + lane * 8) = u.h8;
  }
  __syncthreads();

  // ---- Stage 2: Pi/Pj projection MFMAs, 2 (br,t) pairs per wave ----
  floatx4 pif[2], pjf[2];
#pragma unroll
  for (int pp = 0; pp < 2; ++pp) {
    const int p = w * 2 + pp;   // 0..7
    const int br = p >> 2;
    const int t = p & 3;
    floatx4 z = {0.f, 0.f, 0.f, 0.f};
    pif[pp] = z; pjf[pp] = z;
#pragma unroll
    for (int hh = 0; hh < 2; ++hh) {
      half8 bi = *reinterpret_cast<half8*>(fraglds + (br * 8 + t * 2 + hh) * 512 + lane * 8);
      half8 bj = *reinterpret_cast<half8*>(fraglds + (16 + br * 8 + t * 2 + hh) * 512 + lane * 8);
      pif[pp] = __builtin_amdgcn_mfma_f32_16x16x32_f16(hi[hh], bi, pif[pp], 0, 0, 0);
      pjf[pp] = __builtin_amdgcn_mfma_f32_16x16x32_f16(hj[hh], bj, pjf[pp], 0, 0, 0);
    }
  }
  // pf/pj live in their own region: no alias barrier needed before the writes.
#pragma unroll
  for (int pp = 0; pp < 2; ++pp) {
    const int p = w * 2 + pp;
    *reinterpret_cast<floatx4*>(pflds + (p * 64 + lane) * 4) = pif[pp];
    *reinterpret_cast<floatx4*>(pjlds + (p * 64 + lane) * 4) = pjf[pp];
  }
  __syncthreads();

  // ---- Stage 3: per-wave pickup of Pi/Pj results and We fragments ----
  // pif C-layout at source lane w*16+l15, reg ii  ==  Pi[i0+ii][t*16+l15]
  // pjf C-layout at own lane, reg r               ==  Pj[j0+quad*4+r][t*16+l15]
  float pia_all[2][4][4];
  float pj[2][4][4];
  half8 wf[2][4][2];
#pragma unroll
  for (int br = 0; br < 2; ++br)
#pragma unroll
    for (int t = 0; t < 4; ++t) {
      const int p = br * 4 + t;
      const floatx4 pjv = *reinterpret_cast<const floatx4*>(pjlds + (p * 64 + lane) * 4);
      const floatx4 piv = *reinterpret_cast<const floatx4*>(pflds + (p * 64 + w * 16 + l15) * 4);
#pragma unroll
      for (int r = 0; r < 4; ++r) { pj[br][t][r] = pjv[r]; pia_all[br][t][r] = piv[r]; }
#pragma unroll
      for (int hh = 0; hh < 2; ++hh)
        wf[br][t][hh] = *reinterpret_cast<half8*>(
            fraglds + (32 + br * 8 + t * 2 + hh) * 512 + lane * 8);
    }

  float acc[4][4];
#pragma unroll
  for (int t = 0; t < 4; ++t)
#pragma unroll
    for (int r = 0; r < 4; ++r) acc[t][r] = 0.f;

  // ---- Main loop over this wave's 4 i's ----
#pragma unroll
  for (int ii = 0; ii < 4; ++ii) {
    const int i = i0 + ii;
    half8 a0, a1;
    float av[4];
    if (ii < 2) {
      a0 = cvt2(e_pf[ii][0], e_pf[ii][1]);
      a1 = cvt2(e_pf[ii][2], e_pf[ii][3]);
      av[0] = a_pf[ii].x; av[1] = a_pf[ii].y; av[2] = a_pf[ii].z; av[3] = a_pf[ii].w;
    } else {
      const float* erow = E + ((size_t)((b * 128 + i) * 128 + j0 + l15)) * 64 + quad * 8;
      a0 = cvt2(*reinterpret_cast<const float4*>(erow),
                *reinterpret_cast<const float4*>(erow + 4));
      a1 = cvt2(*reinterpret_cast<const float4*>(erow + 32),
                *reinterpret_cast<const float4*>(erow + 36));
      const float4 av4 = *reinterpret_cast<const float4*>(
          A + (b * 128 + i) * 128 + j0 + quad * 4);
      av[0] = av4.x; av[1] = av4.y; av[2] = av4.z; av[3] = av4.w;
    }

#pragma unroll
    for (int t = 0; t < 4; ++t) {
      floatx4 z = {0.f, 0.f, 0.f, 0.f};
      floatx4 pa = __builtin_amdgcn_mfma_f32_16x16x32_f16(a0, wf[0][t][0], z, 0, 0, 0);
      pa = __builtin_amdgcn_mfma_f32_16x16x32_f16(a1, wf[0][t][1], pa, 0, 0, 0);
      floatx4 pn = __builtin_amdgcn_mfma_f32_16x16x32_f16(a0, wf[1][t][0], z, 0, 0, 0);
      pn = __builtin_amdgcn_mfma_f32_16x16x32_f16(a1, wf[1][t][1], pn, 0, 0, 0);
#pragma unroll
      for (int r = 0; r < 4; ++r) {
        float att = av[r] * (pa[r] + pia_all[0][t][ii] + pj[0][t][r]) + biasv[0][t];
        float cnv = av[r] * (pn[r] + pia_all[1][t][ii] + pj[1][t][r]) + biasv[1][t];
        float ex = __expf(-att);
        float sig = __builtin_amdgcn_rcpf(1.0f + ex);
        acc[t][r] += sig * fmaxf(cnv, 0.f);
      }
    }
  }

  // ---- Epilogue: intra-block reduce (4 waves), then 8-contender atomics ----
  // red aliases frags F0..15 only (dead since stage 2, whose reads complete
  // before the stage-2 barrier) -> no extra barrier needed before the writes.
#pragma unroll
  for (int t = 0; t < 4; ++t)
#pragma unroll
    for (int r = 0; r < 4; ++r)
      red[w][quad * 4 + r][t * 16 + l15] = acc[t][r];
  __syncthreads();

  const int tid = threadIdx.x;
#pragma unroll
  for (int k = 0; k < 4; ++k) {
    int idx = k * 256 + tid;       // 0..1023 over the 16x64 out tile
    int jl = idx >> 6;
    int l = idx & 63;
    float s = red[0][jl][l] + red[1][jl][l] + red[2][jl][l] + red[3][jl][l];
    atomicAdd(out + (b * 128 + j0 + jl) * 64 + l, s);
  }
}

extern "C" void kernel_launch(void* const* d_in, const int* in_sizes, int n_in,
                              void* d_out, int out_size, void* d_ws, size_t ws_size,
                              hipStream_t stream) {
  const float* H = (const float*)d_in[0];
  const float* A = (const float*)d_in[1];
  const float* E = (const float*)d_in[2];
  const float* Wa = (const float*)d_in[3];
  const float* Wn = (const float*)d_in[4];
  const float* ba = (const float*)d_in[5];
  const float* bn = (const float*)d_in[6];
  float* out = (float*)d_out;

  hipMemsetAsync(d_out, 0, (size_t)out_size * sizeof(float), stream);
  amp_fused<<<512, 256, 0, stream>>>(H, A, E, Wa, Wn, ba, bn, out);
}